// Round 3
// baseline (249.947 us; speedup 1.0000x reference)
//
#include <hip/hip_runtime.h>
#include <hip/hip_fp16.h>

#define B_ 64
#define T_ 2048
#define D_ 256
#define U_ 256
#define BT 256            // T rows per score_ctx block
#define NT (BT / 16)      // 16 tiles of 16 rows
#define TC (T_ / BT)      // 8 chunks per batch

typedef _Float16 half8  __attribute__((ext_vector_type(8)));
typedef float    floatx4 __attribute__((ext_vector_type(4)));

typedef const __attribute__((address_space(1))) void cg_void;   // global src for DMA
typedef __attribute__((address_space(3))) void       ls_void;   // LDS dst for DMA

// s_waitcnt imm encode (gfx9): vmcnt[3:0]@bit0, expcnt@4..6(=7: none),
// lgkmcnt@8..11, vmcnt[5:4]@14..15
#define WC_VM8_ONLY   0x0F78   // vmcnt<=8, lgkm free
#define WC_LGKM0_ONLY 0xC07F   // lgkmcnt(0), vmcnt free (63)
#define WC_ALL0       0x0070   // vmcnt(0) lgkmcnt(0)

// ---------------- Kernel 1 (fused prep): qproj (blocks 0..63) + w2t (blocks 64..127) ----------
__global__ void prep_kernel(const float* __restrict__ query,
                            const float* __restrict__ W1_w,
                            const float* __restrict__ W1_b,
                            const float* __restrict__ W2_w,
                            const float* __restrict__ W2_b,
                            float* __restrict__ qb,
                            _Float16* __restrict__ w2t) {
    __shared__ float sh[32 * 33];
    if (blockIdx.x < 64) {
        // qb[b,u] = query[b]·W1[:,u] + W1_b[u] + W2_b[u]
        const int b = blockIdx.x;
        const int u = threadIdx.x;           // 256 threads
        sh[u] = query[b * D_ + u];
        __syncthreads();
        float acc = W1_b[u] + W2_b[u];
#pragma unroll 8
        for (int d = 0; d < D_; ++d)
            acc += sh[d] * W1_w[d * U_ + u];
        qb[b * U_ + u] = acc;
    } else {
        // w2t[u,d] = (fp16) W2[d,u]
        const int bid = blockIdx.x - 64;
        const int tu = bid & 7;
        const int td = bid >> 3;
        const int c  = threadIdx.x & 31;
        const int r0 = threadIdx.x >> 5;
        float* tile = sh;                    // [32][33]
#pragma unroll
        for (int i = 0; i < 4; ++i) {
            int r = r0 + i * 8;
            tile[r * 33 + c] = W2_w[(td * 32 + r) * U_ + tu * 32 + c];
        }
        __syncthreads();
#pragma unroll
        for (int i = 0; i < 4; ++i) {
            int r = r0 + i * 8;              // u within tile
            w2t[(tu * 32 + r) * D_ + td * 32 + c] = (_Float16)tile[c * 33 + r];
        }
    }
}

// ---------------- Kernel 2 (fused): w=exp(score) + partial context, NO max-shift ----------------
// Scores are bounded: |s| <= ||V_w||_1 ~ 10  =>  exp(s) safe in fp32 with zero shift.
// Quad-buffered LDS staging via global_load_lds(16B); raw s_barrier with hand waitcnts:
//   barrier A: s_waitcnt vmcnt(8)  -- drains ONLY tile t's 4 DMAs; 8 stay in flight
//   barrier B: s_waitcnt lgkmcnt(0) -- s_part visibility; vmcnt untouched (prefetch survives)
// XOR-swizzled 16B-chunk layout (chunk cc of row r at LDS chunk r*64 + (cc ^ (r&7))):
// conflict-free DMA writes, balanced b128 MFMA A-reads, 2-way (free) context column reads.
__launch_bounds__(256, 2)
__global__ void score_ctx_kernel(const float* __restrict__ values,
                                 const _Float16* __restrict__ w2t,
                                 const float* __restrict__ qb,
                                 const float* __restrict__ V_w,
                                 float* __restrict__ wexp,
                                 float* __restrict__ pctx,
                                 float* __restrict__ pl) {
    __shared__ __align__(16) float vbuf[4][16 * D_];   // 4 x 16KB fp32 tiles
    __shared__ float s_part[2][16][4];                 // [phase][row][wave]

    const int b     = blockIdx.y;
    const int chunk = blockIdx.x;
    const int tid   = threadIdx.x;
    const int wave  = tid >> 6;
    const int lane  = tid & 63;
    const int n16   = lane & 15;
    const int quad  = lane >> 4;
    const int u0    = wave * 64;

    // --- W2 B-fragments, register-stationary ---
    half8 bfrag[4][8];
#pragma unroll
    for (int ut = 0; ut < 4; ++ut) {
        const int u = u0 + ut * 16 + n16;
#pragma unroll
        for (int k = 0; k < 8; ++k)
            bfrag[ut][k] = *(const half8*)(w2t + u * D_ + k * 32 + quad * 8);
    }
    float qbv[4], vwv[4];
#pragma unroll
    for (int ut = 0; ut < 4; ++ut) {
        const int u = u0 + ut * 16 + n16;
        qbv[ut] = qb[b * U_ + u];
        vwv[ut] = V_w[u];
    }

    const float* vbase = values + (size_t)b * T_ * D_ + (size_t)chunk * BT * D_;

    auto stage = [&](int tile, int bi) {
        const float* src = vbase + tile * 16 * D_;
#pragma unroll
        for (int i = 0; i < 4; ++i) {
            const int r = i * 4 + wave;                          // wave-uniform row
            const float* g = src + r * D_ + ((lane ^ (r & 7)) << 2);
            float* l = &vbuf[bi][r * D_];                        // wave-uniform LDS base
            __builtin_amdgcn_global_load_lds((cg_void*)g, (ls_void*)l, 16, 0, 0);
        }
    };

    stage(0, 0); stage(1, 1); stage(2, 2);    // 12 DMAs in flight per wave

    float c     = 0.f;       // context accumulator: this thread owns d = tid
    float l_run = 0.f;       // sum of exp(score) (identical copies in all threads)

    float* wout = wexp + b * T_ + chunk * BT;

    for (int t = 0; t < NT; ++t) {
        __builtin_amdgcn_s_waitcnt(WC_VM8_ONLY);   // tile t landed (oldest 4 DMAs)
        __builtin_amdgcn_s_barrier();
        // prefetch tile t+3 into vbuf[(t+3)&3] (tail: L2-hot dummy re-read, keeps vmcnt uniform)
        stage((t + 3 < NT) ? t + 3 : t, (t + 3) & 3);

        // --- MFMA: Vp[16 x 64chunk] on vbuf[t&3] ---
        floatx4 acc[4] = {};
        const float* rowbase = &vbuf[t & 3][n16 * D_];
        const int swz = n16 & 7;
#pragma unroll
        for (int k = 0; k < 8; ++k) {
            const int c0 = k * 8 + quad * 2;
            floatx4 q0 = *(const floatx4*)(rowbase + (((c0    ) ^ swz) << 2));
            floatx4 q1 = *(const floatx4*)(rowbase + (((c0 + 1) ^ swz) << 2));
            half8 a;
            a[0] = (_Float16)q0.x; a[1] = (_Float16)q0.y;
            a[2] = (_Float16)q0.z; a[3] = (_Float16)q0.w;
            a[4] = (_Float16)q1.x; a[5] = (_Float16)q1.y;
            a[6] = (_Float16)q1.z; a[7] = (_Float16)q1.w;
#pragma unroll
            for (int ut = 0; ut < 4; ++ut)
                acc[ut] = __builtin_amdgcn_mfma_f32_16x16x32_f16(a, bfrag[ut][k], acc[ut], 0, 0, 0);
        }

        // --- epilogue: tanh + dot with V_w, butterfly over n16 ---
        float part[4];
#pragma unroll
        for (int r = 0; r < 4; ++r) {
            float s = 0.f;
#pragma unroll
            for (int ut = 0; ut < 4; ++ut) {
                float x  = acc[ut][r] + qbv[ut];
                float e  = __expf(2.f * x);
                float th = 1.f - __fdividef(2.f, e + 1.f);   // tanh(x)
                s += th * vwv[ut];
            }
            part[r] = s;
        }
#pragma unroll
        for (int m = 1; m < 16; m <<= 1)
#pragma unroll
            for (int r = 0; r < 4; ++r)
                part[r] += __shfl_xor(part[r], m, 16);
        if (n16 == 0)
#pragma unroll
            for (int r = 0; r < 4; ++r)
                s_part[t & 1][quad * 4 + r][wave] = part[r];

        __builtin_amdgcn_s_waitcnt(WC_LGKM0_ONLY); // DS drained; prefetch DMAs untouched
        __builtin_amdgcn_s_barrier();

        // --- context accumulate: all threads, no serial section ---
        const int ccx = tid >> 2, lo = tid & 3;
#pragma unroll
        for (int r = 0; r < 16; ++r) {
            floatx4 sp = *(const floatx4*)&s_part[t & 1][r][0];  // broadcast b128
            float s = (sp.x + sp.y) + (sp.z + sp.w);
            float w = __expf(s);
            l_run += w;
            c += w * vbuf[t & 3][r * D_ + ((ccx ^ (r & 7)) << 2) + lo];
            if (tid == r) wout[t * 16 + r] = w;                  // raw exp(score) for attn
        }
    }

    pctx[(b * TC + chunk) * D_ + tid] = c;
    if (tid == 0) pl[b * TC + chunk] = l_run;
    __builtin_amdgcn_s_waitcnt(WC_ALL0);           // drain dummy DMAs before endpgm
}

// ---------------- Kernel 3: combine partials -> ctx, attn ----------------
__global__ void finalize_kernel(const float* __restrict__ pctx,
                                const float* __restrict__ pl,
                                const float* __restrict__ wexp,
                                float* __restrict__ ctx,
                                float* __restrict__ attn) {
    const int b = blockIdx.x, tid = threadIdx.x;   // 256 threads
    float L = 0.f;
#pragma unroll
    for (int i = 0; i < TC; ++i) L += pl[b * TC + i];
    const float invL = 1.f / L;
    float s = 0.f;
#pragma unroll
    for (int i = 0; i < TC; ++i) s += pctx[(b * TC + i) * D_ + tid];
    ctx[b * D_ + tid] = s * invL;
#pragma unroll
    for (int j = 0; j < T_ / 256; ++j) {
        const int t = j * 256 + tid;
        attn[b * T_ + t] = wexp[b * T_ + t] * invL;
    }
}

extern "C" void kernel_launch(void* const* d_in, const int* in_sizes, int n_in,
                              void* d_out, int out_size, void* d_ws, size_t ws_size,
                              hipStream_t stream) {
    const float* query  = (const float*)d_in[0];
    const float* values = (const float*)d_in[1];
    const float* W1_w   = (const float*)d_in[2];
    const float* W1_b   = (const float*)d_in[3];
    const float* W2_w   = (const float*)d_in[4];
    const float* W2_b   = (const float*)d_in[5];
    const float* V_w    = (const float*)d_in[6];
    // d_in[7] = V_b: softmax is shift-invariant -> no effect on either output.

    float* out  = (float*)d_out;
    float* ctx  = out;                  // [B, D]
    float* attn = out + B_ * D_;        // [B, T]

    char* ws = (char*)d_ws;
    float*    qb   = (float*)ws;                                 // B*U fp32     (64 KB)
    _Float16* w2t  = (_Float16*)(ws + (64 << 10));               // U*D fp16     (128 KB)
    float*    wexp = (float*)(ws + (192 << 10));                 // B*T fp32     (512 KB)
    float*    pctx = (float*)(ws + (704 << 10));                 // B*TC*D fp32  (512 KB)
    float*    pl   = (float*)(ws + (1216 << 10));                // B*TC fp32    (2 KB)

    prep_kernel     <<<dim3(128),     dim3(256), 0, stream>>>(query, W1_w, W1_b, W2_w, W2_b, qb, w2t);
    score_ctx_kernel<<<dim3(TC, B_),  dim3(256), 0, stream>>>(values, w2t, qb, V_w, wexp, pctx, pl);
    finalize_kernel <<<dim3(B_),      dim3(256), 0, stream>>>(pctx, pl, wexp, ctx, attn);
}